// Round 1
// baseline (648.742 us; speedup 1.0000x reference)
//
#include <hip/hip_runtime.h>
#include <math.h>

// CCAttention: gather off-diagonal positions, QKV projections, criss-cross
// attention (41 keys per head: 1 self + 40 pattern), output projection.
// Round 0: correct fp32 baseline. GEMMs are tiled fp32 (no MFMA yet).

#define NHEADS 12

__device__ __forceinline__ float wave_sum(float x) {
#pragma unroll
  for (int off = 32; off; off >>= 1) x += __shfl_xor(x, off, 64);
  return x;
}
__device__ __forceinline__ float wave_max(float x) {
#pragma unroll
  for (int off = 32; off; off >>= 1) x = fmaxf(x, __shfl_xor(x, off, 64));
  return x;
}

// ---------------------------------------------------------------------------
// Kernel 1: compact nonzero mask positions (row-major order == jnp.nonzero)
// pos2l[flat(b,r,c)] = l (or -1), lidx[l] = flat(b,r,c)
// single block, 1024 threads, Hillis-Steele scan in LDS.
// ---------------------------------------------------------------------------
__global__ __launch_bounds__(1024) void build_idx(const float* __restrict__ mask,
                                                  int total,
                                                  int* __restrict__ pos2l,
                                                  int* __restrict__ lidx) {
  __shared__ int cnt[1024];
  int t = threadIdx.x;
  int per = (total + 1023) >> 10;
  int begin = t * per;
  int end = begin + per; if (end > total) end = total;
  if (begin > total) begin = total;
  int c = 0;
  for (int i = begin; i < end; ++i) c += (mask[i] > 0.f) ? 1 : 0;
  cnt[t] = c;
  __syncthreads();
  for (int off = 1; off < 1024; off <<= 1) {
    int vv = (t >= off) ? cnt[t - off] : 0;
    __syncthreads();
    cnt[t] += vv;
    __syncthreads();
  }
  int excl = cnt[t] - c;  // exclusive prefix
  for (int i = begin; i < end; ++i) {
    if (mask[i] > 0.f) { pos2l[i] = excl; lidx[excl] = i; ++excl; }
    else pos2l[i] = -1;
  }
}

// ---------------------------------------------------------------------------
// Kernel 2: tiled fp32 GEMM, optional row-gather on A.
// C[m][n] = sum_k A[rowbase(m) + k] * B[k][n] + bias[n]
// rowbase(m) = lidx[m]*strideA if GATHER else m*strideA.
// BM=BN=64, BK=16, 256 threads, 4x4 per thread.
// ---------------------------------------------------------------------------
#define BM 64
#define BN 64
#define BK 16

template <bool GATHER>
__global__ __launch_bounds__(256) void gemm_rg(const float* __restrict__ A,
                                               const int* __restrict__ lidx,
                                               const float* __restrict__ B,
                                               const float* __restrict__ bias,
                                               float* __restrict__ C,
                                               int M, int K, int N, int strideA) {
  __shared__ float As[BM][BK + 1];   // +1 pad: conflict-free column reads
  __shared__ float Bs[BK][BN];
  int tid = threadIdx.x;
  int tr = tid >> 4;   // 0..15 -> row group
  int tc = tid & 15;   // 0..15 -> col group
  int m0 = blockIdx.y * BM;
  int n0 = blockIdx.x * BN;

  // precompute the 4 A-row bases this thread stages
  long abase[4];
  int ma = tid >> 4;   // 0..15
  int ka = tid & 15;   // 0..15
#pragma unroll
  for (int it = 0; it < 4; ++it) {
    int gm = m0 + ma + 16 * it;
    if (gm < M) abase[it] = GATHER ? (long)lidx[gm] * strideA : (long)gm * strideA;
    else        abase[it] = -1;
  }

  float acc[4][4] = {};
  for (int k0 = 0; k0 < K; k0 += BK) {
    // stage A (64 rows x 16 k)
#pragma unroll
    for (int it = 0; it < 4; ++it) {
      int m = ma + 16 * it;
      float vv = (abase[it] >= 0) ? A[abase[it] + k0 + ka] : 0.f;
      As[m][ka] = vv;
    }
    // stage B (16 k x 64 n)
    int nb = tid & 63;
    int kb = tid >> 6;  // 0..3
#pragma unroll
    for (int it = 0; it < 4; ++it) {
      int k = kb + 4 * it;
      Bs[k][nb] = B[(long)(k0 + k) * N + n0 + nb];
    }
    __syncthreads();
#pragma unroll
    for (int k = 0; k < BK; ++k) {
      float a[4];
#pragma unroll
      for (int i = 0; i < 4; ++i) a[i] = As[tr * 4 + i][k];
      float4 b4 = *reinterpret_cast<const float4*>(&Bs[k][tc * 4]);
      float bv[4] = {b4.x, b4.y, b4.z, b4.w};
#pragma unroll
      for (int i = 0; i < 4; ++i)
#pragma unroll
        for (int j = 0; j < 4; ++j) acc[i][j] += a[i] * bv[j];
    }
    __syncthreads();
  }
#pragma unroll
  for (int i = 0; i < 4; ++i) {
    int gm = m0 + tr * 4 + i;
    if (gm >= M) continue;
#pragma unroll
    for (int j = 0; j < 4; ++j) {
      int gn = n0 + tc * 4 + j;
      C[(long)gm * N + gn] = acc[i][j] + bias[gn];
    }
  }
}

// ---------------------------------------------------------------------------
// Kernel 3: attention. One wave per (l, h). lane = head-dim (hd must be 64).
// 41 keys: slot 0 = self (+1.0 additive), slots 1..n = pattern p = h%4.
// ---------------------------------------------------------------------------
__global__ __launch_bounds__(256) void attn_k(const float* __restrict__ q,
                                              const float* __restrict__ k,
                                              const float* __restrict__ v,
                                              const float* __restrict__ mask,
                                              const int* __restrict__ lidx,
                                              const int* __restrict__ pos2l,
                                              float* __restrict__ ctx,
                                              int L, int n) {
  __shared__ float sc[4][64];
  __shared__ int   sl[4][64];
  int w = threadIdx.x >> 6;
  int lane = threadIdx.x & 63;
  int gw = blockIdx.x * 4 + w;
  bool valid = gw < L * NHEADS;
  int gwc = valid ? gw : 0;
  int l = gwc / NHEADS;
  int h = gwc - l * NHEADS;
  int p = h & 3;
  int nn = n * n;
  int fidx = lidx[l];
  int bi = fidx / nn;
  int rem = fidx - bi * nn;
  int ri = rem / n;
  int ci = rem - ri * n;
  const float* mb = mask + (long)bi * nn;

  float qd = q[((long)l * NHEADS + h) * 64 + lane];

  // self score (additive mask = +1.0 per reference)
  {
    float kd = k[((long)l * NHEADS + h) * 64 + lane];
    float d = wave_sum(qd * kd);
    if (lane == 0) { sc[w][0] = d * 0.125f + 1.0f; sl[w][0] = l; }
  }
  for (int j = 0; j < n; ++j) {
    int pos; float mval;
    if (p == 0)      { pos = ri * n + j; mval = mb[pos] * ((j != ci) ? 1.f : 0.f); }
    else if (p == 1) { pos = j * n + ci; mval = mb[pos] * ((j != ri) ? 1.f : 0.f); }
    else if (p == 2) { pos = j * n + ri; mval = mb[pos]; }
    else             { pos = ci * n + j; mval = mb[pos]; }
    int l2 = pos2l[(long)bi * nn + pos];
    float d = 0.f;
    if (l2 >= 0) {  // wave-uniform branch
      float kd = k[((long)l2 * NHEADS + h) * 64 + lane];
      d = wave_sum(qd * kd);
    }
    float s = d * 0.125f + (1.f - mval) * -10000.f;
    if (lane == 0) { sc[w][1 + j] = s; sl[w][1 + j] = l2; }
  }
  __syncthreads();

  int Kk = n + 1;
  float x = (lane < Kk) ? sc[w][lane] : -INFINITY;
  float mx = wave_max(x);
  float e = (lane < Kk) ? __expf(x - mx) : 0.f;
  float ssum = wave_sum(e);
  float pr = e / ssum;
  __syncthreads();
  if (lane < Kk) sc[w][lane] = pr;
  __syncthreads();

  float acc = 0.f;
  for (int j = 0; j < Kk; ++j) {
    int l2 = sl[w][j];
    if (l2 >= 0) acc += sc[w][j] * v[((long)l2 * NHEADS + h) * 64 + lane];
  }
  if (valid) ctx[((long)l * NHEADS + h) * 64 + lane] = acc;
}

// ---------------------------------------------------------------------------
extern "C" void kernel_launch(void* const* d_in, const int* in_sizes, int n_in,
                              void* d_out, int out_size, void* d_ws, size_t ws_size,
                              hipStream_t stream) {
  const float* Input  = (const float*)d_in[0];
  const float* hidden = (const float*)d_in[1];
  const float* mask   = (const float*)d_in[2];
  const float* Wq = (const float*)d_in[3];
  const float* bq = (const float*)d_in[4];
  const float* Wk = (const float*)d_in[5];
  const float* bk = (const float*)d_in[6];
  const float* Wv = (const float*)d_in[7];
  const float* bv = (const float*)d_in[8];
  const float* Wo = (const float*)d_in[9];
  const float* bo = (const float*)d_in[10];

  int H = (int)llround(sqrt((double)in_sizes[3]));   // 768
  int total = in_sizes[2];                           // b*n*n = 3200
  int L = out_size / H;                              // 3120
  int bn = total - L;                                // b*n = 80
  int n = total / bn;                                // 40
  // b = bn / n (unused on host beyond index math done on device)

  // workspace layout
  char* p = (char*)d_ws;
  auto alignup = [](size_t x) { return (x + 255) & ~(size_t)255; };
  int* lidx = (int*)p;        p += alignup((size_t)L * 4);
  int* pos2l = (int*)p;       p += alignup((size_t)total * 4);
  float* qb = (float*)p;      p += alignup((size_t)L * H * 4);
  float* kb = (float*)p;      p += alignup((size_t)L * H * 4);
  float* vb = (float*)p;      p += alignup((size_t)L * H * 4);
  float* ctxb = (float*)p;    p += alignup((size_t)L * H * 4);

  build_idx<<<1, 1024, 0, stream>>>(mask, total, pos2l, lidx);

  dim3 gemmGrid(H / BN, (L + BM - 1) / BM);
  gemm_rg<true><<<gemmGrid, 256, 0, stream>>>(hidden, lidx, Wq, bq, qb, L, H, H, H);
  gemm_rg<true><<<gemmGrid, 256, 0, stream>>>(Input,  lidx, Wk, bk, kb, L, H, H, H);
  gemm_rg<true><<<gemmGrid, 256, 0, stream>>>(Input,  lidx, Wv, bv, vb, L, H, H, H);

  int nwaves = L * NHEADS;
  attn_k<<<(nwaves + 3) / 4, 256, 0, stream>>>(qb, kb, vb, mask, lidx, pos2l, ctxb, L, n);

  gemm_rg<false><<<gemmGrid, 256, 0, stream>>>(ctxb, nullptr, Wo, bo, (float*)d_out, L, H, H, H);
}

// Round 2
// 214.956 us; speedup vs baseline: 3.0180x; 3.0180x over previous
//
#include <hip/hip_runtime.h>
#include <hip/hip_bf16.h>
#include <math.h>

#define NHEADS 12

typedef __attribute__((ext_vector_type(4))) float f32x4;
typedef __attribute__((ext_vector_type(8))) short bf16x8;

__device__ __forceinline__ float wave_sum(float x) {
#pragma unroll
  for (int off = 32; off; off >>= 1) x += __shfl_xor(x, off, 64);
  return x;
}
__device__ __forceinline__ float wave_max(float x) {
#pragma unroll
  for (int off = 32; off; off >>= 1) x = fmaxf(x, __shfl_xor(x, off, 64));
  return x;
}
__device__ __forceinline__ unsigned short f2bf(float x) {
  __hip_bfloat16 h = __float2bfloat16(x);
  return *reinterpret_cast<unsigned short*>(&h);
}
__device__ __forceinline__ float bf2f(unsigned short u) {
  union { unsigned int i; float f; } c; c.i = ((unsigned int)u) << 16; return c.f;
}

// ---------------------------------------------------------------------------
// Kernel 1: compact nonzero mask positions (row-major == jnp.nonzero order)
// ---------------------------------------------------------------------------
__global__ __launch_bounds__(1024) void build_idx(const float* __restrict__ mask,
                                                  int total,
                                                  int* __restrict__ pos2l,
                                                  int* __restrict__ lidx) {
  __shared__ int cnt[1024];
  int t = threadIdx.x;
  int per = (total + 1023) >> 10;
  int begin = t * per;
  int end = begin + per; if (end > total) end = total;
  if (begin > total) begin = total;
  int c = 0;
  for (int i = begin; i < end; ++i) c += (mask[i] > 0.f) ? 1 : 0;
  cnt[t] = c;
  __syncthreads();
  for (int off = 1; off < 1024; off <<= 1) {
    int vv = (t >= off) ? cnt[t - off] : 0;
    __syncthreads();
    cnt[t] += vv;
    __syncthreads();
  }
  int excl = cnt[t] - c;
  for (int i = begin; i < end; ++i) {
    if (mask[i] > 0.f) { pos2l[i] = excl; lidx[excl] = i; ++excl; }
    else pos2l[i] = -1;
  }
}

// ---------------------------------------------------------------------------
// Kernel 2: weight transpose + fp32->bf16 convert. W[k][n] f32 -> Wt[n][k] bf16
// ---------------------------------------------------------------------------
__global__ __launch_bounds__(256) void wconv(const float* __restrict__ W0, const float* __restrict__ W1,
                                             const float* __restrict__ W2, const float* __restrict__ W3,
                                             unsigned short* __restrict__ T0, unsigned short* __restrict__ T1,
                                             unsigned short* __restrict__ T2, unsigned short* __restrict__ T3,
                                             int H) {
  const float* W = (blockIdx.z == 0) ? W0 : (blockIdx.z == 1) ? W1 : (blockIdx.z == 2) ? W2 : W3;
  unsigned short* T = (blockIdx.z == 0) ? T0 : (blockIdx.z == 1) ? T1 : (blockIdx.z == 2) ? T2 : T3;
  __shared__ float tile[32][33];
  int k0 = blockIdx.y * 32, n0 = blockIdx.x * 32;
  int t = threadIdx.x;
  int kk = t >> 3, n4 = (t & 7) * 4;
  float4 v = *reinterpret_cast<const float4*>(W + (size_t)(k0 + kk) * H + n0 + n4);
  tile[n4 + 0][kk] = v.x; tile[n4 + 1][kk] = v.y; tile[n4 + 2][kk] = v.z; tile[n4 + 3][kk] = v.w;
  __syncthreads();
  int nn2 = t >> 3, k4 = (t & 7) * 4;
#pragma unroll
  for (int e = 0; e < 4; ++e)
    T[(size_t)(n0 + nn2) * H + k0 + k4 + e] = f2bf(tile[nn2][k4 + e]);
}

// ---------------------------------------------------------------------------
// Kernel 3: gather rows via lidx + fp32->bf16. 8 elems per thread.
// ---------------------------------------------------------------------------
__global__ __launch_bounds__(256) void gatherconv(const float* __restrict__ hidden,
                                                  const float* __restrict__ input,
                                                  const int* __restrict__ lidx,
                                                  unsigned short* __restrict__ Aq,
                                                  unsigned short* __restrict__ Akv,
                                                  int L, int H) {
  int i = blockIdx.x * 256 + threadIdx.x;
  int per = H / 8;                       // 96
  if (i >= L * per) return;
  int row = i / per;
  int sub = (i - row * per) * 8;
  size_t src = (size_t)lidx[row] * H + sub;
  size_t dst = (size_t)row * H + sub;
  {
    float4 a = *reinterpret_cast<const float4*>(hidden + src);
    float4 b = *reinterpret_cast<const float4*>(hidden + src + 4);
    bf16x8 st;
    st[0]=f2bf(a.x); st[1]=f2bf(a.y); st[2]=f2bf(a.z); st[3]=f2bf(a.w);
    st[4]=f2bf(b.x); st[5]=f2bf(b.y); st[6]=f2bf(b.z); st[7]=f2bf(b.w);
    *reinterpret_cast<bf16x8*>(Aq + dst) = st;
  }
  {
    float4 a = *reinterpret_cast<const float4*>(input + src);
    float4 b = *reinterpret_cast<const float4*>(input + src + 4);
    bf16x8 st;
    st[0]=f2bf(a.x); st[1]=f2bf(a.y); st[2]=f2bf(a.z); st[3]=f2bf(a.w);
    st[4]=f2bf(b.x); st[5]=f2bf(b.y); st[6]=f2bf(b.z); st[7]=f2bf(b.w);
    *reinterpret_cast<bf16x8*>(Akv + dst) = st;
  }
}

// ---------------------------------------------------------------------------
// Kernel 4: bf16 MFMA GEMM.  C[m][n] = A[m][k] * Bt[n][k] + bias[n]
// BM=128 BN=64 BK=64, 256 threads (4 waves 2x2), 16x16x32 MFMA.
// LDS XOR-swizzled (slot ^= row&7) via pre-swizzled global_load_lds source.
// ---------------------------------------------------------------------------
#define GBM 128
#define GBN 64
#define GBK 64

template <bool OUT_BF16>
__global__ __launch_bounds__(256) void gemm_bf16(const unsigned short* __restrict__ A,
                                                 const unsigned short* __restrict__ Bt,
                                                 const float* __restrict__ bias,
                                                 void* __restrict__ C,
                                                 int M, int N, int K) {
  __shared__ unsigned short sA[GBM * GBK];   // [row][8 slots of 8 elems], swizzled
  __shared__ unsigned short sB[GBN * GBK];
  int tid = threadIdx.x;
  int wid = tid >> 6, lane = tid & 63;
  int wm = wid >> 1, wn = wid & 1;
  int m0 = blockIdx.y * GBM, n0 = blockIdx.x * GBN;
  int lr = lane & 15, lq = lane >> 4;
  f32x4 acc[4][2] = {};

  for (int k0 = 0; k0 < K; k0 += GBK) {
    // stage A: 1024 16-B chunks, 4 rounds x 4 waves x 64 lanes
#pragma unroll
    for (int r = 0; r < 4; ++r) {
      int c = (r * 4 + wid) * 64 + lane;
      int row = c >> 3, sl = c & 7;
      int sg = sl ^ (row & 7);
      const unsigned short* g = A + (size_t)(m0 + row) * K + k0 + sg * 8;
      __builtin_amdgcn_global_load_lds((const __attribute__((address_space(1))) unsigned int*)g,
                                       (__attribute__((address_space(3))) unsigned int*)(sA + (size_t)(r * 4 + wid) * 512),
                                       16, 0, 0);
    }
    // stage B: 512 chunks, 2 rounds
#pragma unroll
    for (int r = 0; r < 2; ++r) {
      int c = (r * 4 + wid) * 64 + lane;
      int row = c >> 3, sl = c & 7;
      int sg = sl ^ (row & 7);
      const unsigned short* g = Bt + (size_t)(n0 + row) * K + k0 + sg * 8;
      __builtin_amdgcn_global_load_lds((const __attribute__((address_space(1))) unsigned int*)g,
                                       (__attribute__((address_space(3))) unsigned int*)(sB + (size_t)(r * 4 + wid) * 512),
                                       16, 0, 0);
    }
    __syncthreads();
#pragma unroll
    for (int ks = 0; ks < 2; ++ks) {
      bf16x8 af[4], bfr[2];
#pragma unroll
      for (int i = 0; i < 4; ++i) {
        int row = wm * 64 + i * 16 + lr;
        int slot = (ks * 4 + lq) ^ (row & 7);
        af[i] = *reinterpret_cast<const bf16x8*>(sA + row * 64 + slot * 8);
      }
#pragma unroll
      for (int j = 0; j < 2; ++j) {
        int rn = wn * 32 + j * 16 + lr;
        int slot = (ks * 4 + lq) ^ (rn & 7);
        bfr[j] = *reinterpret_cast<const bf16x8*>(sB + rn * 64 + slot * 8);
      }
#pragma unroll
      for (int i = 0; i < 4; ++i)
#pragma unroll
        for (int j = 0; j < 2; ++j)
          acc[i][j] = __builtin_amdgcn_mfma_f32_16x16x32_bf16(af[i], bfr[j], acc[i][j], 0, 0, 0);
    }
    __syncthreads();
  }

#pragma unroll
  for (int i = 0; i < 4; ++i) {
#pragma unroll
    for (int j = 0; j < 2; ++j) {
      int gcol = n0 + wn * 32 + j * 16 + lr;
      float bv = bias[gcol];
      int rbase = m0 + wm * 64 + i * 16 + lq * 4;
#pragma unroll
      for (int r = 0; r < 4; ++r) {
        int gm = rbase + r;
        if (gm >= M) continue;
        float val = acc[i][j][r] + bv;
        if (OUT_BF16) ((unsigned short*)C)[(size_t)gm * N + gcol] = f2bf(val);
        else          ((float*)C)[(size_t)gm * N + gcol] = val;
      }
    }
  }
}

// ---------------------------------------------------------------------------
// Kernel 5: scatter k,v (bf16, l-major) into head-major grids
// kg[bi][h][r][c][64], zeros at missing positions. 8 elems per thread.
// ---------------------------------------------------------------------------
__global__ __launch_bounds__(256) void scatter_kv(const unsigned short* __restrict__ kb,
                                                  const unsigned short* __restrict__ vb,
                                                  const int* __restrict__ pos2l,
                                                  unsigned short* __restrict__ kg,
                                                  unsigned short* __restrict__ vg,
                                                  int n, int total, int H) {
  int i = blockIdx.x * 256 + threadIdx.x;
  int per = H / 8;                 // 96 chunks per position
  if (i >= total * per) return;
  int pos = i / per;
  int r8 = i - pos * per;
  int h = r8 >> 3;
  int d8 = (r8 & 7) * 8;
  int nn = n * n;
  int bi = pos / nn;
  int rc = pos - bi * nn;
  int r = rc / n;
  int c = rc - r * n;
  int l2 = pos2l[pos];
  size_t dst = ((((size_t)bi * NHEADS + h) * n + r) * n + c) * 64 + d8;
  bf16x8 zk = {}, zv = {};
  if (l2 >= 0) {
    size_t src = (size_t)l2 * H + h * 64 + d8;
    zk = *reinterpret_cast<const bf16x8*>(kb + src);
    zv = *reinterpret_cast<const bf16x8*>(vb + src);
  }
  *reinterpret_cast<bf16x8*>(kg + dst) = zk;
  *reinterpret_cast<bf16x8*>(vg + dst) = zv;
}

// ---------------------------------------------------------------------------
// Kernel 6: attention. One block (256 thr) per l. Grid-layout bf16 k/v.
// Phase 1: 492 (h,j) score dots thread-parallel. Phase 2: per-head softmax
// (wave-wide over 41 lanes). Phase 3: PV, lane = d, coalesced v rows.
// ---------------------------------------------------------------------------
__global__ __launch_bounds__(256) void attn2(const unsigned short* __restrict__ qb,
                                             const unsigned short* __restrict__ kg,
                                             const unsigned short* __restrict__ vg,
                                             const float* __restrict__ mask,
                                             const int* __restrict__ lidx,
                                             unsigned short* __restrict__ ctx,
                                             int L, int n, int H) {
  __shared__ float qs[768];
  __shared__ float S[NHEADS][44];
  int bid = blockIdx.x;
  int l = ((L & 7) == 0) ? (bid & 7) * (L >> 3) + (bid >> 3) : bid;  // XCD swizzle
  int tid = threadIdx.x;
  int nn = n * n;
  int fidx = lidx[l];
  int bi = fidx / nn;
  int rem = fidx - bi * nn;
  int ri = rem / n;
  int ci = rem - ri * n;
  const float* mb = mask + (size_t)bi * nn;

  for (int i = tid; i < H; i += 256) qs[i] = bf2f(qb[(size_t)l * H + i]);
  __syncthreads();

  int NK = n + 1;                        // 41
  int items = NHEADS * NK;               // 492
  for (int wi = tid; wi < items; wi += 256) {
    int h = wi / NK;
    int j = wi - h * NK;
    int p = h & 3;
    int pos; float add;
    if (j == 0) { pos = ri * n + ci; add = 1.0f; }
    else {
      int jj = j - 1;
      float mval;
      if (p == 0)      { pos = ri * n + jj; mval = mb[pos] * ((jj != ci) ? 1.f : 0.f); }
      else if (p == 1) { pos = jj * n + ci; mval = mb[pos] * ((jj != ri) ? 1.f : 0.f); }
      else if (p == 2) { pos = jj * n + ri; mval = mb[pos]; }
      else             { pos = ci * n + jj; mval = mb[pos]; }
      add = (1.f - mval) * -10000.f;
    }
    const unsigned short* krow = kg + ((((size_t)bi * NHEADS + h) * nn) + pos) * 64;
    float acc = 0.f;
#pragma unroll
    for (int it = 0; it < 8; ++it) {
      bf16x8 kv = *reinterpret_cast<const bf16x8*>(krow + it * 8);
#pragma unroll
      for (int e = 0; e < 8; ++e)
        acc += qs[h * 64 + it * 8 + e] * bf2f((unsigned short)kv[e]);
    }
    S[h][j] = acc * 0.125f + add;
  }
  __syncthreads();

  int wid = tid >> 6, lane = tid & 63;
#pragma unroll
  for (int t3 = 0; t3 < 3; ++t3) {
    int h = wid + 4 * t3;
    float x = (lane < NK) ? S[h][lane] : -3.0e38f;
    float mx = wave_max(x);
    float e = (lane < NK) ? __expf(x - mx) : 0.f;
    float sm = wave_sum(e);
    if (lane < NK) S[h][lane] = e / sm;
  }
  __syncthreads();

  int d = tid & 63;
  int hq = tid >> 6;
#pragma unroll
  for (int t3 = 0; t3 < 3; ++t3) {
    int h = hq + 4 * t3;
    int p = h & 3;
    const unsigned short* vbase = vg + (((size_t)bi * NHEADS + h) * nn) * 64;
    float acc = S[h][0] * bf2f(vbase[(size_t)(ri * n + ci) * 64 + d]);
#pragma unroll 4
    for (int jj = 0; jj < n; ++jj) {
      int pos = (p == 0) ? ri * n + jj : (p == 1) ? jj * n + ci : (p == 2) ? jj * n + ri : ci * n + jj;
      acc += S[h][1 + jj] * bf2f(vbase[(size_t)pos * 64 + d]);
    }
    ctx[(size_t)l * H + h * 64 + d] = f2bf(acc);
  }
}

// ---------------------------------------------------------------------------
extern "C" void kernel_launch(void* const* d_in, const int* in_sizes, int n_in,
                              void* d_out, int out_size, void* d_ws, size_t ws_size,
                              hipStream_t stream) {
  const float* Input  = (const float*)d_in[0];
  const float* hidden = (const float*)d_in[1];
  const float* mask   = (const float*)d_in[2];
  const float* Wq = (const float*)d_in[3];
  const float* bq = (const float*)d_in[4];
  const float* Wk = (const float*)d_in[5];
  const float* bk = (const float*)d_in[6];
  const float* Wv = (const float*)d_in[7];
  const float* bv = (const float*)d_in[8];
  const float* Wo = (const float*)d_in[9];
  const float* bo = (const float*)d_in[10];

  int H = (int)llround(sqrt((double)in_sizes[3]));   // 768
  int total = in_sizes[2];                           // b*n*n = 3200
  int L = out_size / H;                              // 3120
  int bn = total - L;                                // b*n = 80
  int n = total / bn;                                // 40
  int b = bn / n;                                    // 2
  int mtiles = (L + GBM - 1) / GBM;                  // 25
  int Mpad = mtiles * GBM;                           // 3200

  size_t gridElems = (size_t)b * NHEADS * n * n * 64;   // 2457600
  size_t aElems = (size_t)Mpad * H;                     // 2457600
  size_t bigE = (gridElems > aElems) ? gridElems : aElems;

  char* p = (char*)d_ws;
  auto take = [&](size_t bytes) { char* r = p; p += (bytes + 255) & ~(size_t)255; return r; };
  int* lidx  = (int*)take((size_t)L * 4);
  int* pos2l = (int*)take((size_t)total * 4);
  unsigned short* Wqt = (unsigned short*)take((size_t)H * H * 2);
  unsigned short* Wkt = (unsigned short*)take((size_t)H * H * 2);
  unsigned short* Wvt = (unsigned short*)take((size_t)H * H * 2);
  unsigned short* Wot = (unsigned short*)take((size_t)H * H * 2);
  unsigned short* Aq  = (unsigned short*)take(bigE * 2);   // later: kgrid
  unsigned short* Akv = (unsigned short*)take(bigE * 2);   // later: vgrid
  unsigned short* qb2 = (unsigned short*)take(aElems * 2);
  unsigned short* kb2 = (unsigned short*)take(aElems * 2); // later: ctx
  unsigned short* vb2 = (unsigned short*)take(aElems * 2);
  unsigned short* kgrid = Aq;
  unsigned short* vgrid = Akv;
  unsigned short* ctxb = kb2;

  build_idx<<<1, 1024, 0, stream>>>(mask, total, pos2l, lidx);
  wconv<<<dim3(H / 32, H / 32, 4), 256, 0, stream>>>(Wq, Wk, Wv, Wo, Wqt, Wkt, Wvt, Wot, H);
  {
    int nthr = L * (H / 8);
    gatherconv<<<(nthr + 255) / 256, 256, 0, stream>>>(hidden, Input, lidx, Aq, Akv, L, H);
  }
  dim3 gg(H / GBN, mtiles);
  gemm_bf16<true><<<gg, 256, 0, stream>>>(Aq,  Wqt, bq, qb2, L, H, H);
  gemm_bf16<true><<<gg, 256, 0, stream>>>(Akv, Wkt, bk, kb2, L, H, H);
  gemm_bf16<true><<<gg, 256, 0, stream>>>(Akv, Wvt, bv, vb2, L, H, H);
  {
    int nthr = total * (H / 8);
    scatter_kv<<<(nthr + 255) / 256, 256, 0, stream>>>(kb2, vb2, pos2l, kgrid, vgrid, n, total, H);
  }
  attn2<<<L, 256, 0, stream>>>(qb2, kgrid, vgrid, mask, lidx, ctxb, L, n, H);
  gemm_bf16<false><<<gg, 256, 0, stream>>>(ctxb, Wot, bo, (float*)d_out, L, H, H);
}

// Round 3
// 96.693 us; speedup vs baseline: 6.7093x; 2.2231x over previous
//
#include <hip/hip_runtime.h>
#include <hip/hip_bf16.h>
#include <math.h>

#define NHEADS 12

typedef __attribute__((ext_vector_type(4))) float f32x4;
typedef __attribute__((ext_vector_type(8))) short bf16x8;

__device__ __forceinline__ unsigned short f2bf(float x) {
  __hip_bfloat16 h = __float2bfloat16(x);
  return *reinterpret_cast<unsigned short*>(&h);
}
__device__ __forceinline__ float bf2f(unsigned short u) {
  union { unsigned int i; float f; } c; c.i = ((unsigned int)u) << 16; return c.f;
}

// ---------------------------------------------------------------------------
// Kernel 1: compact nonzero mask positions (row-major == jnp.nonzero order)
// + concat bk|bv into bkv (for the merged KV GEMM).
// ---------------------------------------------------------------------------
__global__ __launch_bounds__(1024) void build_idx(const float* __restrict__ mask,
                                                  int total,
                                                  int* __restrict__ pos2l,
                                                  int* __restrict__ lidx,
                                                  const float* __restrict__ bk,
                                                  const float* __restrict__ bv,
                                                  float* __restrict__ bkv,
                                                  int H) {
  __shared__ int cnt[1024];
  int t = threadIdx.x;
  if (t < H) { bkv[t] = bk[t]; bkv[H + t] = bv[t]; }
  int per = (total + 1023) >> 10;
  int begin = t * per;
  int end = begin + per; if (end > total) end = total;
  if (begin > total) begin = total;
  int c = 0;
  for (int i = begin; i < end; ++i) c += (mask[i] > 0.f) ? 1 : 0;
  cnt[t] = c;
  __syncthreads();
  for (int off = 1; off < 1024; off <<= 1) {
    int vv = (t >= off) ? cnt[t - off] : 0;
    __syncthreads();
    cnt[t] += vv;
    __syncthreads();
  }
  int excl = cnt[t] - c;
  for (int i = begin; i < end; ++i) {
    if (mask[i] > 0.f) { pos2l[i] = excl; lidx[excl] = i; ++excl; }
    else pos2l[i] = -1;
  }
}

// ---------------------------------------------------------------------------
// Kernel 2: weight transpose + fp32->bf16. W[k][n] f32 -> Wt[n][k] bf16.
// z=0: Wq->Wqt; z=1: Wk->Wkvt rows 0..H-1; z=2: Wv->Wkvt rows H..2H-1; z=3: Wo->Wot
// ---------------------------------------------------------------------------
__global__ __launch_bounds__(256) void wconv(const float* __restrict__ W0, const float* __restrict__ W1,
                                             const float* __restrict__ W2, const float* __restrict__ W3,
                                             unsigned short* __restrict__ T0, unsigned short* __restrict__ T1,
                                             unsigned short* __restrict__ T2, unsigned short* __restrict__ T3,
                                             int H) {
  const float* W = (blockIdx.z == 0) ? W0 : (blockIdx.z == 1) ? W1 : (blockIdx.z == 2) ? W2 : W3;
  unsigned short* T = (blockIdx.z == 0) ? T0 : (blockIdx.z == 1) ? T1 : (blockIdx.z == 2) ? T2 : T3;
  __shared__ float tile[32][33];
  int k0 = blockIdx.y * 32, n0 = blockIdx.x * 32;
  int t = threadIdx.x;
  int kk = t >> 3, n4 = (t & 7) * 4;
  float4 v = *reinterpret_cast<const float4*>(W + (size_t)(k0 + kk) * H + n0 + n4);
  tile[n4 + 0][kk] = v.x; tile[n4 + 1][kk] = v.y; tile[n4 + 2][kk] = v.z; tile[n4 + 3][kk] = v.w;
  __syncthreads();
  int nn2 = t >> 3, k4 = (t & 7) * 4;
#pragma unroll
  for (int e = 0; e < 4; ++e)
    T[(size_t)(n0 + nn2) * H + k0 + k4 + e] = f2bf(tile[nn2][k4 + e]);
}

// ---------------------------------------------------------------------------
// Kernel 3: gather rows via lidx + fp32->bf16.
// ---------------------------------------------------------------------------
__global__ __launch_bounds__(256) void gatherconv(const float* __restrict__ hidden,
                                                  const float* __restrict__ input,
                                                  const int* __restrict__ lidx,
                                                  unsigned short* __restrict__ Aq,
                                                  unsigned short* __restrict__ Akv,
                                                  int L, int H) {
  int i = blockIdx.x * 256 + threadIdx.x;
  int per = H / 8;
  if (i >= L * per) return;
  int row = i / per;
  int sub = (i - row * per) * 8;
  size_t src = (size_t)lidx[row] * H + sub;
  size_t dst = (size_t)row * H + sub;
  {
    float4 a = *reinterpret_cast<const float4*>(hidden + src);
    float4 b = *reinterpret_cast<const float4*>(hidden + src + 4);
    bf16x8 st;
    st[0]=f2bf(a.x); st[1]=f2bf(a.y); st[2]=f2bf(a.z); st[3]=f2bf(a.w);
    st[4]=f2bf(b.x); st[5]=f2bf(b.y); st[6]=f2bf(b.z); st[7]=f2bf(b.w);
    *reinterpret_cast<bf16x8*>(Aq + dst) = st;
  }
  {
    float4 a = *reinterpret_cast<const float4*>(input + src);
    float4 b = *reinterpret_cast<const float4*>(input + src + 4);
    bf16x8 st;
    st[0]=f2bf(a.x); st[1]=f2bf(a.y); st[2]=f2bf(a.z); st[3]=f2bf(a.w);
    st[4]=f2bf(b.x); st[5]=f2bf(b.y); st[6]=f2bf(b.z); st[7]=f2bf(b.w);
    *reinterpret_cast<bf16x8*>(Akv + dst) = st;
  }
}

// ---------------------------------------------------------------------------
// Kernel 4: bf16 MFMA GEMM.  C[m][n] = A[m][k] * Bt[n][k] + bias[n]
// BM=128 BN=64 BK=64, 256 threads (4 waves 2x2), 16x16x32 MFMA.
// ---------------------------------------------------------------------------
#define GBM 128
#define GBN 64
#define GBK 64

template <bool OUT_BF16>
__global__ __launch_bounds__(256) void gemm_bf16(const unsigned short* __restrict__ A,
                                                 const unsigned short* __restrict__ Bt,
                                                 const float* __restrict__ bias,
                                                 void* __restrict__ C,
                                                 int M, int N, int K) {
  __shared__ unsigned short sA[GBM * GBK];
  __shared__ unsigned short sB[GBN * GBK];
  int tid = threadIdx.x;
  int wid = tid >> 6, lane = tid & 63;
  int wm = wid >> 1, wn = wid & 1;
  int m0 = blockIdx.y * GBM, n0 = blockIdx.x * GBN;
  int lr = lane & 15, lq = lane >> 4;
  f32x4 acc[4][2] = {};

  for (int k0 = 0; k0 < K; k0 += GBK) {
#pragma unroll
    for (int r = 0; r < 4; ++r) {
      int c = (r * 4 + wid) * 64 + lane;
      int row = c >> 3, sl = c & 7;
      int sg = sl ^ (row & 7);
      const unsigned short* g = A + (size_t)(m0 + row) * K + k0 + sg * 8;
      __builtin_amdgcn_global_load_lds((const __attribute__((address_space(1))) unsigned int*)g,
                                       (__attribute__((address_space(3))) unsigned int*)(sA + (size_t)(r * 4 + wid) * 512),
                                       16, 0, 0);
    }
#pragma unroll
    for (int r = 0; r < 2; ++r) {
      int c = (r * 4 + wid) * 64 + lane;
      int row = c >> 3, sl = c & 7;
      int sg = sl ^ (row & 7);
      const unsigned short* g = Bt + (size_t)(n0 + row) * K + k0 + sg * 8;
      __builtin_amdgcn_global_load_lds((const __attribute__((address_space(1))) unsigned int*)g,
                                       (__attribute__((address_space(3))) unsigned int*)(sB + (size_t)(r * 4 + wid) * 512),
                                       16, 0, 0);
    }
    __syncthreads();
#pragma unroll
    for (int ks = 0; ks < 2; ++ks) {
      bf16x8 af[4], bfr[2];
#pragma unroll
      for (int i = 0; i < 4; ++i) {
        int row = wm * 64 + i * 16 + lr;
        int slot = (ks * 4 + lq) ^ (row & 7);
        af[i] = *reinterpret_cast<const bf16x8*>(sA + row * 64 + slot * 8);
      }
#pragma unroll
      for (int j = 0; j < 2; ++j) {
        int rn = wn * 32 + j * 16 + lr;
        int slot = (ks * 4 + lq) ^ (rn & 7);
        bfr[j] = *reinterpret_cast<const bf16x8*>(sB + rn * 64 + slot * 8);
      }
#pragma unroll
      for (int i = 0; i < 4; ++i)
#pragma unroll
        for (int j = 0; j < 2; ++j)
          acc[i][j] = __builtin_amdgcn_mfma_f32_16x16x32_bf16(af[i], bfr[j], acc[i][j], 0, 0, 0);
    }
    __syncthreads();
  }

#pragma unroll
  for (int i = 0; i < 4; ++i) {
#pragma unroll
    for (int j = 0; j < 2; ++j) {
      int gcol = n0 + wn * 32 + j * 16 + lr;
      float bv = bias[gcol];
      int rbase = m0 + wm * 64 + i * 16 + lq * 4;
#pragma unroll
      for (int r = 0; r < 4; ++r) {
        int gm = rbase + r;
        if (gm >= M) continue;
        float val = acc[i][j][r] + bv;
        if (OUT_BF16) ((unsigned short*)C)[(size_t)gm * N + gcol] = f2bf(val);
        else          ((float*)C)[(size_t)gm * N + gcol] = val;
      }
    }
  }
}

// ---------------------------------------------------------------------------
// Kernel 5: criss-cross attention, row/col-batched.
// Block = (bi, p, r0, h3): head h = p + 4*h3 attends the 40 keys of
// grid row r0 (p=0,3) or col r0 (p=1,2); queries are the valid positions of
// row r0 (p=0,2) or col r0 (p=1,3). Self key handled as 41st slot (+1.0).
// 128 threads: stage K/V rows -> LDS; A: (c,jhalf) 20-key dots -> S;
// B: (c) softmax over 41; C: (c,dhalf) PV over 40 LDS rows + self-v.
// ---------------------------------------------------------------------------
__global__ __launch_bounds__(128) void attn3(const unsigned short* __restrict__ qb,
                                             const unsigned short* __restrict__ KVb,
                                             const float* __restrict__ mask,
                                             const int* __restrict__ pos2l,
                                             unsigned short* __restrict__ ctx,
                                             int n, int H) {
  __shared__ unsigned short Ks[40 * 72];
  __shared__ unsigned short Vs[40 * 72];
  __shared__ float S[40][42];
  __shared__ float mrow[40];
  __shared__ int qlist[40];

  int bx = blockIdx.x;
  int r0 = bx % n;
  int h3 = (bx / n) % 3;
  int p = (bx / (3 * n)) % 4;
  int bi = bx / (12 * n);
  int h = p + 4 * h3;
  int nn = n * n;
  bool rowkeys = (p == 0 || p == 3);
  bool rowq = (p == 0 || p == 2);
  bool excl = (p < 2);
  int t = threadIdx.x;
  int H2 = 2 * H;

  // stage K/V rows (t<80: half=t/40 -> K or V, j=t%40) + mask/qlist (t<40)
  if (t < 80) {
    int half = t / 40, j = t % 40;
    int keypos = rowkeys ? (r0 * n + j) : (j * n + r0);
    int l2 = pos2l[bi * nn + keypos];
    unsigned short* dst = (half ? Vs : Ks) + j * 72;
    if (l2 >= 0) {
      const unsigned short* src = KVb + (size_t)l2 * H2 + half * H + h * 64;
#pragma unroll
      for (int e8 = 0; e8 < 8; ++e8)
        *reinterpret_cast<bf16x8*>(dst + e8 * 8) = *reinterpret_cast<const bf16x8*>(src + e8 * 8);
    } else {
      bf16x8 z = {};
#pragma unroll
      for (int e8 = 0; e8 < 8; ++e8) *reinterpret_cast<bf16x8*>(dst + e8 * 8) = z;
    }
  }
  if (t < 40) {
    mrow[t] = rowkeys ? mask[bi * nn + r0 * n + t] : mask[bi * nn + t * n + r0];
    int qpos = rowq ? (r0 * n + t) : (t * n + r0);
    qlist[t] = pos2l[bi * nn + qpos];
  }
  __syncthreads();

  int c = t % 40;
  int role = t / 40;          // 0,1 active; 2 idle (t 80..127)
  int lq = (t < 80) ? qlist[c] : -1;

  // ---- phase A: scores ----
  if (lq >= 0) {
    float qf[64];
    const unsigned short* qp = qb + (size_t)lq * H + h * 64;
#pragma unroll
    for (int e8 = 0; e8 < 8; ++e8) {
      bf16x8 t8 = *reinterpret_cast<const bf16x8*>(qp + e8 * 8);
#pragma unroll
      for (int e = 0; e < 8; ++e) qf[e8 * 8 + e] = bf2f((unsigned short)t8[e]);
    }
    int j0 = role * 20;
#pragma unroll 2
    for (int j = j0; j < j0 + 20; ++j) {
      float acc = 0.f;
#pragma unroll
      for (int e8 = 0; e8 < 8; ++e8) {
        bf16x8 kv = *reinterpret_cast<const bf16x8*>(Ks + j * 72 + e8 * 8);
#pragma unroll
        for (int e = 0; e < 8; ++e) acc = fmaf(qf[e8 * 8 + e], bf2f((unsigned short)kv[e]), acc);
      }
      float mval = mrow[j] * ((excl && j == c) ? 0.f : 1.f);
      S[c][j] = acc * 0.125f + (1.f - mval) * -10000.f;
    }
    if (role == 0) {  // self key = kv row of the query itself (41st slot, +1.0)
      const unsigned short* kp = KVb + (size_t)lq * H2 + h * 64;
      float acc = 0.f;
#pragma unroll
      for (int e8 = 0; e8 < 8; ++e8) {
        bf16x8 kv = *reinterpret_cast<const bf16x8*>(kp + e8 * 8);
#pragma unroll
        for (int e = 0; e < 8; ++e) acc = fmaf(qf[e8 * 8 + e], bf2f((unsigned short)kv[e]), acc);
      }
      S[c][40] = acc * 0.125f + 1.0f;
    }
  }
  __syncthreads();

  // ---- phase B: softmax over 41 ----
  if (t < 40 && qlist[t] >= 0) {
    float mx = -3.0e38f;
    for (int j = 0; j <= 40; ++j) mx = fmaxf(mx, S[t][j]);
    float sum = 0.f;
    for (int j = 0; j <= 40; ++j) { float e = __expf(S[t][j] - mx); S[t][j] = e; sum += e; }
    float inv = 1.f / sum;
    for (int j = 0; j <= 40; ++j) S[t][j] *= inv;
  }
  __syncthreads();

  // ---- phase C: PV ----
  if (lq >= 0) {
    int d0 = role * 32;
    const unsigned short* vsp = KVb + (size_t)lq * H2 + H + h * 64 + d0;
    float pself = S[c][40];
#pragma unroll
    for (int ch = 0; ch < 4; ++ch) {
      int dd = d0 + ch * 8;
      float facc[8];
      bf16x8 vself = *reinterpret_cast<const bf16x8*>(vsp + ch * 8);
#pragma unroll
      for (int e = 0; e < 8; ++e) facc[e] = pself * bf2f((unsigned short)vself[e]);
      for (int j = 0; j < 40; ++j) {
        float pj = S[c][j];
        bf16x8 vv = *reinterpret_cast<const bf16x8*>(Vs + j * 72 + dd);
#pragma unroll
        for (int e = 0; e < 8; ++e) facc[e] = fmaf(pj, bf2f((unsigned short)vv[e]), facc[e]);
      }
      bf16x8 st;
#pragma unroll
      for (int e = 0; e < 8; ++e) st[e] = f2bf(facc[e]);
      *reinterpret_cast<bf16x8*>(ctx + (size_t)lq * H + h * 64 + dd) = st;
    }
  }
}

// ---------------------------------------------------------------------------
extern "C" void kernel_launch(void* const* d_in, const int* in_sizes, int n_in,
                              void* d_out, int out_size, void* d_ws, size_t ws_size,
                              hipStream_t stream) {
  const float* Input  = (const float*)d_in[0];
  const float* hidden = (const float*)d_in[1];
  const float* mask   = (const float*)d_in[2];
  const float* Wq = (const float*)d_in[3];
  const float* bq = (const float*)d_in[4];
  const float* Wk = (const float*)d_in[5];
  const float* bk = (const float*)d_in[6];
  const float* Wv = (const float*)d_in[7];
  const float* bv = (const float*)d_in[8];
  const float* Wo = (const float*)d_in[9];
  const float* bo = (const float*)d_in[10];

  int H = (int)llround(sqrt((double)in_sizes[3]));   // 768
  int total = in_sizes[2];                           // b*n*n = 3200
  int L = out_size / H;                              // 3120
  int bn = total - L;                                // b*n = 80
  int n = total / bn;                                // 40
  int b = bn / n;                                    // 2
  int mtiles = (L + GBM - 1) / GBM;                  // 25
  int Mpad = mtiles * GBM;                           // 3200
  size_t aElems = (size_t)Mpad * H;

  char* p = (char*)d_ws;
  auto take = [&](size_t bytes) { char* r = p; p += (bytes + 255) & ~(size_t)255; return r; };
  int* lidx  = (int*)take((size_t)L * 4);
  int* pos2l = (int*)take((size_t)total * 4);
  float* bkv = (float*)take((size_t)2 * H * 4);
  unsigned short* Wqt  = (unsigned short*)take((size_t)H * H * 2);
  unsigned short* Wot  = (unsigned short*)take((size_t)H * H * 2);
  unsigned short* Wkvt = (unsigned short*)take((size_t)2 * H * H * 2);
  unsigned short* Aq   = (unsigned short*)take(aElems * 2);
  unsigned short* Akv  = (unsigned short*)take(aElems * 2);
  unsigned short* qb2  = (unsigned short*)take(aElems * 2);
  unsigned short* KVb  = (unsigned short*)take(aElems * 2 * 2);
  unsigned short* ctxb = (unsigned short*)take(aElems * 2);

  build_idx<<<1, 1024, 0, stream>>>(mask, total, pos2l, lidx, bk, bv, bkv, H);
  wconv<<<dim3(H / 32, H / 32, 4), 256, 0, stream>>>(Wq, Wk, Wv, Wo, Wqt, Wkvt, Wkvt + (size_t)H * H, Wot, H);
  {
    int nthr = L * (H / 8);
    gatherconv<<<(nthr + 255) / 256, 256, 0, stream>>>(hidden, Input, lidx, Aq, Akv, L, H);
  }
  gemm_bf16<true><<<dim3(H / GBN, mtiles), 256, 0, stream>>>(Aq,  Wqt,  bq,  qb2, L, H,     H);
  gemm_bf16<true><<<dim3(2 * H / GBN, mtiles), 256, 0, stream>>>(Akv, Wkvt, bkv, KVb, L, 2 * H, H);
  attn3<<<b * 4 * 3 * n, 128, 0, stream>>>(qb2, KVb, mask, pos2l, ctxb, n, H);
  gemm_bf16<false><<<dim3(H / GBN, mtiles), 256, 0, stream>>>(ctxb, Wot, bo, (float*)d_out, L, H, H);
}